// Round 6
// baseline (1197.248 us; speedup 1.0000x reference)
//
#include <hip/hip_runtime.h>
#include <math.h>

#define PIX   16384       // H*W
#define NB    8
#define CIN   256

typedef __attribute__((ext_vector_type(8))) short    short8;   // bf16x8 frag (4 VGPR)
typedef __attribute__((ext_vector_type(4))) float    f32x4;
typedef __attribute__((ext_vector_type(4))) unsigned short us4;
typedef __attribute__((ext_vector_type(8))) unsigned short us8;

__device__ __forceinline__ float bf2f(unsigned short h) {
  return __uint_as_float(((unsigned int)h) << 16);
}
__device__ __forceinline__ unsigned short f2bf(float f) {  // round-nearest-even
  unsigned int u = __float_as_uint(f);
  return (unsigned short)((u + 0x7FFFu + ((u >> 16) & 1u)) >> 16);
}
__device__ __forceinline__ float gelu_f(float v) {
  return 0.5f * v * (1.f + erff(v * 0.70710678118654752f));
}

// max over the 16 lanes of each DPP row (l16 group) via rotate-reduce — pure VALU
__device__ __forceinline__ float rowmax16(float v) {
  v = fmaxf(v, __uint_as_float(__builtin_amdgcn_update_dpp(
        __float_as_uint(v), __float_as_uint(v), 0x121, 0xF, 0xF, false)));  // row_ror:1
  v = fmaxf(v, __uint_as_float(__builtin_amdgcn_update_dpp(
        __float_as_uint(v), __float_as_uint(v), 0x122, 0xF, 0xF, false)));  // row_ror:2
  v = fmaxf(v, __uint_as_float(__builtin_amdgcn_update_dpp(
        __float_as_uint(v), __float_as_uint(v), 0x124, 0xF, 0xF, false)));  // row_ror:4
  v = fmaxf(v, __uint_as_float(__builtin_amdgcn_update_dpp(
        __float_as_uint(v), __float_as_uint(v), 0x128, 0xF, 0xF, false)));  // row_ror:8
  return v;
}

// ---------------------------------------------------------------- zero
__global__ void zero_kernel(float* p, int n) {
  int i = blockIdx.x * blockDim.x + threadIdx.x;
  if (i < n) p[i] = 0.f;
}

// ---------------------------------------------------- weight prep (bf16)
__global__ void prep_weights(const float* __restrict__ pw_f, const float* __restrict__ mw_f,
                             const float* __restrict__ w0, const float* __restrict__ w1,
                             unsigned short* __restrict__ pw, unsigned short* __restrict__ mw,
                             unsigned short* __restrict__ w0t, unsigned short* __restrict__ w1t) {
  const int S1 = 512 * 256, S2 = 256 * 256, S3 = 512 * 512, S4 = 256 * 512;
  int i = blockIdx.x * 256 + threadIdx.x;
  if (i < S1) { pw[i] = f2bf(pw_f[i]); return; }
  i -= S1;
  if (i < S2) { mw[i] = f2bf(mw_f[i]); return; }
  i -= S2;
  if (i < S3) { int o = i >> 9, k = i & 511; w0t[i] = f2bf(w0[k * 512 + o]); return; }
  i -= S3;
  if (i < S4) { int o = i >> 9, k = i & 511; w1t[i] = f2bf(w1[k * 256 + o]); }
}

// ------------------------------------------- x: NCHW fp32 -> NHWC bf16
__global__ __launch_bounds__(256) void x_to_nhwc(const float* __restrict__ x,
                                                 unsigned short* __restrict__ xT) {
  __shared__ float tile[64][65];
  const int t = threadIdx.x;
  const int p0 = blockIdx.x * 64, c0 = blockIdx.y * 64, n = blockIdx.z;
#pragma unroll
  for (int i = 0; i < 4; i++) {
    const int c = i * 16 + (t >> 4);
    const float4 v = *(const float4*)(x + ((size_t)(n * 256 + c0 + c) << 14) + p0 + (t & 15) * 4);
    tile[c][(t & 15) * 4]     = v.x;
    tile[c][(t & 15) * 4 + 1] = v.y;
    tile[c][(t & 15) * 4 + 2] = v.z;
    tile[c][(t & 15) * 4 + 3] = v.w;
  }
  __syncthreads();
#pragma unroll
  for (int i = 0; i < 4; i++) {
    const int pp = i * 16 + (t >> 4);
    const int cl = (t & 15) * 4;
    us4 o;
    o.x = f2bf(tile[cl][pp]); o.y = f2bf(tile[cl + 1][pp]);
    o.z = f2bf(tile[cl + 2][pp]); o.w = f2bf(tile[cl + 3][pp]);
    *(us4*)&xT[(((size_t)n << 14) + p0 + pp) * 256 + c0 + cl] = o;
  }
}

// ------------------------------------------------- MFMA GEMM v2 (no LDS)
// Y[n][p][o] = sum_k A[o][k]*B[n][p][k] + bias[o] (optional gelu).
// A row-major [M][K], B NHWC [n][p][K]: both already in MFMA fragment layout,
// so fragments are loaded straight from global into registers. Barrier-free
// fully-unrolled K-loop; A reuse via L2, B reuse via L3. Identical fragment
// and accumulation order as the LDS version -> bitwise-identical results.
template<int KI, int K1I, bool CONCAT, bool GELU, bool STATS>
__global__ __launch_bounds__(256, 2) void mfma_gemm_v2(
    const unsigned short* __restrict__ A, const float* __restrict__ bias,
    const unsigned short* __restrict__ B1, const unsigned short* __restrict__ B2,
    unsigned short* __restrict__ Y, int M,
    int astride, int bstride, float* __restrict__ sums) {
  __shared__ float r1[4], r2[4];
  const int t = threadIdx.x;
  const int lane = t & 63, w = t >> 6;
  const int quad = lane >> 4, l16 = lane & 15;
  const int p0 = blockIdx.x * 128, m0 = blockIdx.y * 128;
  const int n = blockIdx.z;
  const int wm = w & 1, wn = w >> 1;
  constexpr int K2I = (KI - K1I) > 0 ? (KI - K1I) : 1;

  A += (size_t)n * astride;
  const size_t nb = ((size_t)n << 14);

  const unsigned short* abase  = A + (size_t)(m0 + wm * 64 + l16) * KI + quad * 8;
  const unsigned short* b1base = B1 + (nb + p0 + wn * 64 + l16) * (size_t)K1I + quad * 8;
  const unsigned short* b2base = CONCAT
      ? B2 + (nb + p0 + wn * 64 + l16) * (size_t)K2I + quad * 8 : B1;

  f32x4 acc[4][4];
#pragma unroll
  for (int im = 0; im < 4; im++)
#pragma unroll
    for (int in = 0; in < 4; in++) acc[im][in] = (f32x4)0.f;

#pragma unroll
  for (int ks = 0; ks < KI / 32; ks++) {
    short8 af[4], bfr[4];
#pragma unroll
    for (int im = 0; im < 4; im++)
      af[im] = *(const short8*)(abase + (size_t)im * 16 * KI + ks * 32);
#pragma unroll
    for (int in = 0; in < 4; in++) {
      if (!CONCAT || (ks * 32) < K1I)
        bfr[in] = *(const short8*)(b1base + (size_t)in * 16 * K1I + ks * 32);
      else
        bfr[in] = *(const short8*)(b2base + (size_t)in * 16 * K2I + (ks * 32 - K1I));
    }
#pragma unroll
    for (int im = 0; im < 4; im++)
#pragma unroll
      for (int in = 0; in < 4; in++)
        acc[im][in] = __builtin_amdgcn_mfma_f32_16x16x32_bf16(af[im], bfr[in], acc[im][in], 0, 0, 0);
  }

  float s = 0.f, s2 = 0.f;
#pragma unroll
  for (int im = 0; im < 4; im++) {
    const int om = m0 + (wm * 4 + im) * 16 + quad * 4;
    const f32x4 bv = *(const f32x4*)(bias + (size_t)n * bstride + om);
#pragma unroll
    for (int in = 0; in < 4; in++) {
      const int p = p0 + (wn * 4 + in) * 16 + l16;
      float v0 = acc[im][in].x + bv.x;
      float v1 = acc[im][in].y + bv.y;
      float v2 = acc[im][in].z + bv.z;
      float v3 = acc[im][in].w + bv.w;
      if (GELU) { v0 = gelu_f(v0); v1 = gelu_f(v1); v2 = gelu_f(v2); v3 = gelu_f(v3); }
      if (STATS) {
        s += (v0 + v1) + (v2 + v3);
        s2 = fmaf(v0, v0, s2); s2 = fmaf(v1, v1, s2);
        s2 = fmaf(v2, v2, s2); s2 = fmaf(v3, v3, s2);
      }
      us4 o4;
      o4.x = f2bf(v0); o4.y = f2bf(v1); o4.z = f2bf(v2); o4.w = f2bf(v3);
      *(us4*)&Y[(nb + p) * M + om] = o4;
    }
  }
  if (STATS) {
#pragma unroll
    for (int off = 32; off > 0; off >>= 1) {
      s += __shfl_down(s, off);
      s2 += __shfl_down(s2, off);
    }
    if (lane == 0) { r1[w] = s; r2[w] = s2; }
    __syncthreads();
    if (t == 0) {
      atomicAdd(&sums[2 * n],     (r1[0] + r1[1]) + (r1[2] + r1[3]));
      atomicAdd(&sums[2 * n + 1], (r2[0] + r2[1]) + (r2[2] + r2[3]));
    }
  }
}

// ============================================================= CLUSTER
// m = 0..255 encodes n(3b) f(3b) s1 s2; region = 64x64 px, 64 ch at f*64.

// ---- A: per-8x8-block channel means -> cpnh_g (bf16 l2-normed point half),
//         cval_g (f32 value-half means). grid (slice4, m256), block 256.
__global__ __launch_bounds__(256) void centers_kernel(
    const unsigned short* __restrict__ y, unsigned short* __restrict__ cpnh_g,
    float* __restrict__ cval_g) {
  const int m = blockIdx.y, slice = blockIdx.x;
  const int n = m >> 5, f = (m >> 2) & 7, s1 = (m >> 1) & 1, s2 = m & 1;
  const int t = threadIdx.x;
  __shared__ float cs[16][68];

  const size_t nbase = ((size_t)n << 14);
  const int prow0 = s1 * 64, pcol0 = s2 * 64, ch0 = f * 64;

  {
    const int bl = t >> 4;                 // local block 0..15
    const int b = slice * 16 + bl;         // global block 0..63
    const int tid = t & 15, cg = tid & 7, ph = tid >> 3;
    const int pr0 = prow0 + (b >> 3) * 8 + ph * 4;
    const int pc0 = pcol0 + (b & 7) * 8;
    const unsigned short* yb = y + (nbase + (size_t)pr0 * 128 + pc0) * 512 + ch0 + cg * 8;
    float a8[8] = {0.f, 0.f, 0.f, 0.f, 0.f, 0.f, 0.f, 0.f};
#pragma unroll
    for (int r = 0; r < 4; r++) {
      us8 buf[8];
#pragma unroll
      for (int cc = 0; cc < 8; cc++)
        buf[cc] = *(const us8*)(yb + ((size_t)r * 128 + cc) * 512);
#pragma unroll
      for (int cc = 0; cc < 8; cc++)
#pragma unroll
        for (int j = 0; j < 8; j++) a8[j] += bf2f(buf[cc][j]);
    }
#pragma unroll
    for (int j = 0; j < 8; j++) a8[j] += __shfl_xor(a8[j], 8);
    if (ph == 0) {
      f32x4 o0, o1;
      o0.x = a8[0] * (1.f / 64.f); o0.y = a8[1] * (1.f / 64.f);
      o0.z = a8[2] * (1.f / 64.f); o0.w = a8[3] * (1.f / 64.f);
      o1.x = a8[4] * (1.f / 64.f); o1.y = a8[5] * (1.f / 64.f);
      o1.z = a8[6] * (1.f / 64.f); o1.w = a8[7] * (1.f / 64.f);
      *(f32x4*)&cs[bl][cg * 8]     = o0;
      *(f32x4*)&cs[bl][cg * 8 + 4] = o1;
    }
  }
  __syncthreads();

  if (t < 128) {
    const int bl = t >> 3, jg = t & 7;
    const int bg = slice * 16 + bl;
    if (jg < 8) {
      f32x4 ov;
      ov.x = cs[bl][32 + jg * 4]; ov.y = cs[bl][32 + jg * 4 + 1];
      ov.z = cs[bl][32 + jg * 4 + 2]; ov.w = cs[bl][32 + jg * 4 + 3];
      *(f32x4*)&cval_g[((size_t)(m * 64 + bg) << 5) + jg * 4] = ov;
    }
    float s = 0.f;
#pragma unroll
    for (int cc = 0; cc < 32; cc++) { const float v = cs[bl][cc]; s = fmaf(v, v, s); }
    const float inv = 1.f / fmaxf(sqrtf(s), 1e-12f);
    us4 o;
    o.x = f2bf(cs[bl][jg * 4] * inv);     o.y = f2bf(cs[bl][jg * 4 + 1] * inv);
    o.z = f2bf(cs[bl][jg * 4 + 2] * inv); o.w = f2bf(cs[bl][jg * 4 + 3] * inv);
    *(us4*)&cpnh_g[((size_t)(m * 64 + bg) << 5) + jg * 4] = o;
  }
}

// ---- B: assignment + partial value scatter. grid (slice8, m256), block 256.
// All 8 point-tiles prefetched upfront (16 x 16B loads in flight per lane).
__global__ __launch_bounds__(256, 4) void assign_kernel(
    const unsigned short* __restrict__ y, const unsigned short* __restrict__ cpnh_g,
    const float* __restrict__ alpha_p, const float* __restrict__ beta_p,
    float* __restrict__ svals_g, unsigned char* __restrict__ sbest_g,
    float* __restrict__ accp_v, float* __restrict__ accp_c) {
  const int m = blockIdx.y, slice = blockIdx.x;
  const int n = m >> 5, f = (m >> 2) & 7, s1 = (m >> 1) & 1, s2 = m & 1;
  const int t = threadIdx.x;
  const int wave = t >> 6, lane = t & 63;
  const int quad = lane >> 4, l16 = lane & 15;
  const float alpha = alpha_p[0], beta = beta_p[0];

  __shared__ float accv[64][34];   // [b][0..31]=val acc, [32]=count

  for (int i = t; i < 64 * 34; i += 256) ((float*)accv)[i] = 0.f;

  const size_t nbase = ((size_t)n << 14);
  const int prow0 = s1 * 64, pcol0 = s2 * 64, ch0 = f * 64;

  const short8 cb0 = *(const short8*)&cpnh_g[((size_t)(m * 64 +  0 + l16) << 5) + quad * 8];
  const short8 cb1 = *(const short8*)&cpnh_g[((size_t)(m * 64 + 16 + l16) << 5) + quad * 8];
  const short8 cb2 = *(const short8*)&cpnh_g[((size_t)(m * 64 + 32 + l16) << 5) + quad * 8];
  const short8 cb3 = *(const short8*)&cpnh_g[((size_t)(m * 64 + 48 + l16) << 5) + quad * 8];
  const int sl4 = (((l16 >> 2) << 4) | (l16 & 3)) << 2;  // bpermute src addr
  const int sh = quad << 4;
  __syncthreads();

  auto loadpt = [&](int tile, short8& a, short8& v) {
    const int pidx = slice * 512 + wave * 128 + tile * 16;
    const int pix = (prow0 + (pidx >> 6)) * 128 + pcol0 + (pidx & 63) + l16;
    const unsigned short* yp = y + (nbase + pix) * 512 + ch0 + quad * 8;
    a = *(const short8*)yp;         // point half frag
    v = *(const short8*)(yp + 32);  // value half
  };

  auto compute_tile = [&](int tile, short8 apt, short8 avl) {
    const int pidx = slice * 512 + wave * 128 + tile * 16;

    float nrm = 0.f;
#pragma unroll
    for (int j = 0; j < 8; j++) {
      const float fv = bf2f((unsigned short)apt[j]);
      nrm = fmaf(fv, fv, nrm);
    }
    nrm += __shfl_xor(nrm, 16);
    nrm += __shfl_xor(nrm, 32);
    const float inva = 1.f / fmaxf(sqrtf(nrm), 1e-12f);

    const f32x4 d0 = __builtin_amdgcn_mfma_f32_16x16x32_bf16(apt, cb0, (f32x4)0.f, 0, 0, 0);
    const f32x4 d1 = __builtin_amdgcn_mfma_f32_16x16x32_bf16(apt, cb1, (f32x4)0.f, 0, 0, 0);
    const f32x4 d2 = __builtin_amdgcn_mfma_f32_16x16x32_bf16(apt, cb2, (f32x4)0.f, 0, 0, 0);
    const f32x4 d3 = __builtin_amdgcn_mfma_f32_16x16x32_bf16(apt, cb3, (f32x4)0.f, 0, 0, 0);

    float bv[4]; int bi[4];
#pragma unroll
    for (int r = 0; r < 4; r++) {
      float v = fmaxf(fmaxf(d0[r], d1[r]), fmaxf(d2[r], d3[r]));
      v = rowmax16(v);
      bv[r] = v;
      const unsigned long long m0 = __ballot(d0[r] == v);
      const unsigned long long m1 = __ballot(d1[r] == v);
      const unsigned long long m2 = __ballot(d2[r] == v);
      const unsigned long long m3 = __ballot(d3[r] == v);
      const unsigned f0 = (unsigned)(m0 >> sh) & 0xFFFFu;
      const unsigned f1 = (unsigned)(m1 >> sh) & 0xFFFFu;
      const unsigned f2 = (unsigned)(m2 >> sh) & 0xFFFFu;
      const unsigned f3 = (unsigned)(m3 >> sh) & 0xFFFFu;
      int ii = 48 + __ffs(f3) - 1;             // lowest set bit = smallest idx
      if (f2) ii = 32 + __ffs(f2) - 1;
      if (f1) ii = 16 + __ffs(f1) - 1;
      if (f0) ii = __ffs(f0) - 1;
      bi[r] = ii;
    }

    const float rv01 = (l16 & 1) ? bv[1] : bv[0];
    const float rv23 = (l16 & 1) ? bv[3] : bv[2];
    const float rowv = (l16 & 2) ? rv23 : rv01;
    const int   ri01 = (l16 & 1) ? bi[1] : bi[0];
    const int   ri23 = (l16 & 1) ? bi[3] : bi[2];
    const int   rowi = (l16 & 2) ? ri23 : ri01;
    const unsigned pk = (__float_as_uint(rowv) & ~63u) | (unsigned)rowi;
    const unsigned got = (unsigned)__builtin_amdgcn_ds_bpermute(sl4, (int)pk);
    const int   idx = (int)(got & 63u);
    const float dot = __uint_as_float(got & ~63u);

    const float val = 1.f / (1.f + __expf(-fmaf(alpha, dot * inva, beta)));
    if (quad == 0) {
      svals_g[(size_t)m * 4096 + pidx + l16] = val;
      sbest_g[(size_t)m * 4096 + pidx + l16] = (unsigned char)idx;
    }
#pragma unroll
    for (int j = 0; j < 8; j++)
      atomicAdd(&accv[idx][quad * 8 + j], val * bf2f((unsigned short)avl[j]));
    if (quad == 0) atomicAdd(&accv[idx][32], val);
  };

  {
    short8 a0, v0, a1, v1, a2, v2, a3, v3, a4, v4, a5, v5, a6, v6, a7, v7;
    loadpt(0, a0, v0); loadpt(1, a1, v1); loadpt(2, a2, v2); loadpt(3, a3, v3);
    loadpt(4, a4, v4); loadpt(5, a5, v5); loadpt(6, a6, v6); loadpt(7, a7, v7);
    compute_tile(0, a0, v0); compute_tile(1, a1, v1);
    compute_tile(2, a2, v2); compute_tile(3, a3, v3);
    compute_tile(4, a4, v4); compute_tile(5, a5, v5);
    compute_tile(6, a6, v6); compute_tile(7, a7, v7);
  }
  __syncthreads();

  const size_t pb = ((size_t)(m * 8 + slice)) * 64;
  for (int i = t; i < 2048; i += 256) {
    const int b = i >> 5, q = i & 31;
    accp_v[(pb + b) * 32 + q] = accv[b][q];
  }
  if (t < 64) accp_c[pb + t] = accv[t][32];
}

// ---- D: reduce partial means + gather -> nx. grid (slice8, m256), block 256.
__global__ __launch_bounds__(256) void gather_kernel(
    const float* __restrict__ accp_v, const float* __restrict__ accp_c,
    const float* __restrict__ cval_g, const float* __restrict__ svals_g,
    const unsigned char* __restrict__ sbest_g, unsigned short* __restrict__ nx) {
  const int m = blockIdx.y, slice = blockIdx.x;
  const int n = m >> 5, f = (m >> 2) & 7, s1 = (m >> 1) & 1, s2 = m & 1;
  const int t = threadIdx.x;
  __shared__ float cm[64][34];

  const size_t nbase = ((size_t)n << 14);
  const int prow0 = s1 * 64, pcol0 = s2 * 64;

  for (int i = t; i < 2048; i += 256) {
    const int b = i >> 5, q = i & 31;
    float s = cval_g[((size_t)(m * 64 + b) << 5) + q];
    float c = 1.f;
#pragma unroll
    for (int s8 = 0; s8 < 8; s8++) {
      const size_t pb = ((size_t)(m * 8 + s8)) * 64 + b;
      s += accp_v[pb * 32 + q];
      c += accp_c[pb];
    }
    cm[b][q] = s / c;
  }
  __syncthreads();

#pragma unroll
  for (int pass = 0; pass < 2; pass++) {
    const int l = slice * 512 + pass * 256 + t;
    const int p = (prow0 + (l >> 6)) * 128 + pcol0 + (l & 63);
    const float v = svals_g[(size_t)m * 4096 + l];
    const int b = sbest_g[(size_t)m * 4096 + l];
    unsigned short* nr = nx + (nbase + p) * 256 + f * 32;
#pragma unroll
    for (int q8 = 0; q8 < 4; q8++) {
      const float2 a0 = *(const float2*)&cm[b][q8 * 8];
      const float2 a1 = *(const float2*)&cm[b][q8 * 8 + 2];
      const float2 a2 = *(const float2*)&cm[b][q8 * 8 + 4];
      const float2 a3 = *(const float2*)&cm[b][q8 * 8 + 6];
      us8 o;
      o[0] = f2bf(v * a0.x); o[1] = f2bf(v * a0.y);
      o[2] = f2bf(v * a1.x); o[3] = f2bf(v * a1.y);
      o[4] = f2bf(v * a2.x); o[5] = f2bf(v * a2.y);
      o[6] = f2bf(v * a3.x); o[7] = f2bf(v * a3.y);
      *(us8*)&nr[q8 * 8] = o;
    }
  }
}

// ---------------- GN0 per-(n,c) affine coefficients from fused sums
__global__ void gn_finalize0(const float* __restrict__ sums, const float* __restrict__ g0w,
                             const float* __restrict__ g0b, float* __restrict__ scl,
                             float* __restrict__ bia) {
  const int n = blockIdx.x, c = threadIdx.x;
  const float cntinv = 1.f / (float)(CIN * PIX);
  const float mu = sums[2 * n] * cntinv;
  const float var = sums[2 * n + 1] * cntinv - mu * mu;
  const float rs = rsqrtf(var + 1e-5f);
  const float a = rs * g0w[c];
  scl[n * 256 + c] = a;
  bia[n * 256 + c] = g0b[c] - mu * a;
}

// ---------------- fold GN0 scale into MLP0 weights (per image)
__global__ void w0_scale(const unsigned short* __restrict__ w0t,
                         const float* __restrict__ scl, unsigned short* __restrict__ w0s) {
  const int n = blockIdx.y;
  const int i = blockIdx.x * 256 + threadIdx.x;   // 0..262143
  const int k = i & 511;
  unsigned short v = w0t[i];
  if (k >= 256) v = f2bf(bf2f(v) * scl[n * 256 + k - 256]);
  w0s[(size_t)n * 262144 + i] = v;
}

// ---------------- effective MLP0 bias: b0e[n][o] = b0[o] + sum_k W0n[o][k]*bia[n][k]
__global__ void b0_eff(const unsigned short* __restrict__ w0t, const float* __restrict__ b0,
                       const float* __restrict__ bia, float* __restrict__ b0e) {
  const int n = blockIdx.y;
  const int o = blockIdx.x * 256 + threadIdx.x;   // 0..511
  float s = b0[o];
  const unsigned short* wr = w0t + (size_t)o * 512 + 256;
  const float* br = bia + n * 256;
#pragma unroll 4
  for (int k = 0; k < 256; k++) s = fmaf(bf2f(wr[k]), br[k], s);
  b0e[n * 512 + o] = s;
}

// ------------------- final: GN1 affine + layer_scale + residual, NHWC->NCHW
__global__ __launch_bounds__(256) void final_transpose(
    const unsigned short* __restrict__ u, const float* __restrict__ x,
    const float* __restrict__ sums, const float* __restrict__ g1w,
    const float* __restrict__ g1b, const float* __restrict__ lsc,
    float* __restrict__ out) {
  __shared__ float tile[64][68];
  const int t = threadIdx.x;
  const int p0 = blockIdx.x * 64, c0 = blockIdx.y * 64, n = blockIdx.z;
  {
    const int pl = t >> 2, g = t & 3;
    const unsigned short* up = u + ((((size_t)n << 14) + p0 + pl) << 8) + c0 + g * 16;
    const us8 v0 = *(const us8*)up;
    const us8 v1 = *(const us8*)(up + 8);
#pragma unroll
    for (int j = 0; j < 8; j++) {
      tile[pl][g * 16 + j] = bf2f(v0[j]);
      tile[pl][g * 16 + 8 + j] = bf2f(v1[j]);
    }
  }
  __syncthreads();
  {
    const int cl = t >> 2, g = t & 3;
    const int c = c0 + cl;
    const float cntinv = 1.f / (float)(CIN * PIX);
    const float mu = sums[2 * n] * cntinv;
    const float var = sums[2 * n + 1] * cntinv - mu * mu;
    const float rs = rsqrtf(var + 1e-5f);
    const float gw = rs * g1w[c] * lsc[c];
    const float gb = (g1b[c] - mu * rs * g1w[c]) * lsc[c];
    const size_t rowb = ((size_t)(n * 256 + c) << 14) + p0 + g * 16;
#pragma unroll
    for (int q = 0; q < 4; q++) {
      const float4 xv = *(const float4*)(x + rowb + q * 4);
      float4 o;
      o.x = fmaf(tile[g * 16 + q * 4][cl], gw, gb) + xv.x;
      o.y = fmaf(tile[g * 16 + q * 4 + 1][cl], gw, gb) + xv.y;
      o.z = fmaf(tile[g * 16 + q * 4 + 2][cl], gw, gb) + xv.z;
      o.w = fmaf(tile[g * 16 + q * 4 + 3][cl], gw, gb) + xv.w;
      *(float4*)(out + rowb + q * 4) = o;
    }
  }
}

// ---------------------------------------------------------------- launch
extern "C" void kernel_launch(void* const* d_in, const int* in_sizes, int n_in,
                              void* d_out, int out_size, void* d_ws, size_t ws_size,
                              hipStream_t stream) {
  const float* x       = (const float*)d_in[0];
  const float* proj_w  = (const float*)d_in[1];
  const float* proj_b  = (const float*)d_in[2];
  const float* merge_w = (const float*)d_in[3];
  const float* merge_b = (const float*)d_in[4];
  const float* alpha   = (const float*)d_in[5];
  const float* beta    = (const float*)d_in[6];
  const float* g0w     = (const float*)d_in[7];
  const float* g0b     = (const float*)d_in[8];
  const float* w0      = (const float*)d_in[9];
  const float* b0      = (const float*)d_in[10];
  const float* w1      = (const float*)d_in[11];
  const float* b1      = (const float*)d_in[12];
  const float* g1w     = (const float*)d_in[13];
  const float* g1b     = (const float*)d_in[14];
  const float* lsc     = (const float*)d_in[15];
  float* out = (float*)d_out;

  // workspace (ushort units), ~274 MB; newx + cluster scratch live in d_out
  unsigned short* wsu = (unsigned short*)d_ws;
  unsigned short* xT  = wsu;                      // 8*16384*256
  unsigned short* y   = xT + (size_t)33554432;    // 8*16384*512 (reused as h)
  unsigned short* nx  = y + (size_t)67108864;     // 8*16384*256 (reused as u)
  unsigned short* pw  = nx + (size_t)33554432;    // 512*256
  unsigned short* mw  = pw + 131072;              // 256*256
  unsigned short* w0t = mw + 65536;               // 512*512
  unsigned short* w1t = w0t + 262144;             // 256*512
  unsigned short* w0s = w1t + 131072;             // 8*512*512
  float* sums = (float*)(w0s + (size_t)2097152);  // 32
  float* scl0 = sums + 32;                        // 8*256
  float* bia0 = scl0 + 2048;                      // 8*256
  float* b0e  = bia0 + 2048;                      // 8*512
  unsigned short* newx = (unsigned short*)d_out;  // scratch inside out (64MB)

  // cluster scratch in the upper half of d_out (dead before final_transpose)
  float* svals_g = (float*)((char*)d_out + 67108864);       // 256*4096 f32 (4MB)
  float* cval_g  = svals_g + 1048576;                       // 256*64*32 f32 (2MB)
  float* accp_v  = cval_g + 524288;                         // 256*8*64*32 f32 (16.8MB)
  float* accp_c  = accp_v + 4194304;                        // 256*8*64 f32 (0.5MB)
  unsigned short* cpnh_g = (unsigned short*)(accp_c + 131072);  // 256*64*32 bf16 (1MB)
  unsigned char*  sbest_g = (unsigned char*)(cpnh_g + 524288);  // 256*4096 u8 (1MB)

  zero_kernel<<<1, 64, 0, stream>>>(sums, 32);
  prep_weights<<<2304, 256, 0, stream>>>(proj_w, merge_w, w0, w1, pw, mw, w0t, w1t);
  x_to_nhwc<<<dim3(256, 4, NB), 256, 0, stream>>>(x, xT);

  // proj: y[n][p][512] = pw @ xT
  mfma_gemm_v2<256, 256, false, false, false><<<dim3(128, 4, NB), 256, 0, stream>>>(
      pw, proj_b, xT, nullptr, y, 512, 0, 0, nullptr);

  // cluster (split)
  centers_kernel<<<dim3(4, 256), 256, 0, stream>>>(y, cpnh_g, cval_g);
  assign_kernel<<<dim3(8, 256), 256, 0, stream>>>(
      y, cpnh_g, alpha, beta, svals_g, sbest_g, accp_v, accp_c);
  gather_kernel<<<dim3(8, 256), 256, 0, stream>>>(
      accp_v, accp_c, cval_g, svals_g, sbest_g, nx);

  // merge: newx = mw @ nx, fused GN0 stats -> sums[0..15]
  mfma_gemm_v2<256, 256, false, false, true><<<dim3(128, 2, NB), 256, 0, stream>>>(
      mw, merge_b, nx, nullptr, newx, 256, 0, 0, sums);

  // GN0 affine coefficients, folded weights & bias
  gn_finalize0<<<NB, 256, 0, stream>>>(sums, g0w, g0b, scl0, bia0);
  w0_scale<<<dim3(1024, NB), 256, 0, stream>>>(w0t, scl0, w0s);
  b0_eff<<<dim3(2, NB), 256, 0, stream>>>(w0t, b0, bia0, b0e);

  // MLP0: h = gelu(w0s_n @ [xT ; newx] + b0e_n)   (h reuses y)
  mfma_gemm_v2<512, 256, true, true, false><<<dim3(128, 4, NB), 256, 0, stream>>>(
      w0s, b0e, xT, newx, y, 512, 262144, 512, nullptr);

  // MLP1: u = w1t @ h + b1, fused GN1 stats -> sums[16..31]   (u reuses nx)
  mfma_gemm_v2<512, 512, false, false, true><<<dim3(128, 2, NB), 256, 0, stream>>>(
      w1t, b1, y, nullptr, nx, 256, 0, 0, sums + 16);

  // final transpose/residual
  final_transpose<<<dim3(256, 4, NB), 256, 0, stream>>>(
      nx, x, sums + 16, g1w, g1b, lsc, out);
}

// Round 7
// 1002.734 us; speedup vs baseline: 1.1940x; 1.1940x over previous
//
#include <hip/hip_runtime.h>
#include <math.h>

#define PIX   16384       // H*W
#define NB    8
#define CIN   256

typedef __attribute__((ext_vector_type(8))) short    short8;   // bf16x8 frag (4 VGPR)
typedef __attribute__((ext_vector_type(4))) float    f32x4;
typedef __attribute__((ext_vector_type(4))) unsigned short us4;
typedef __attribute__((ext_vector_type(8))) unsigned short us8;

__device__ __forceinline__ float bf2f(unsigned short h) {
  return __uint_as_float(((unsigned int)h) << 16);
}
__device__ __forceinline__ unsigned short f2bf(float f) {  // round-nearest-even
  unsigned int u = __float_as_uint(f);
  return (unsigned short)((u + 0x7FFFu + ((u >> 16) & 1u)) >> 16);
}
__device__ __forceinline__ float gelu_f(float v) {
  return 0.5f * v * (1.f + erff(v * 0.70710678118654752f));
}

// order-preserving f32 -> u32 map (unsigned compare == float compare)
__device__ __forceinline__ unsigned fmono(float f) {
  const unsigned u = __float_as_uint(f);
  return (u & 0x80000000u) ? ~u : (u | 0x80000000u);
}

// max/min over the 16 lanes of each DPP row — pure VALU rotate-reduce
__device__ __forceinline__ unsigned umax16(unsigned v) {
  unsigned t;
  t = (unsigned)__builtin_amdgcn_update_dpp((int)v, (int)v, 0x121, 0xF, 0xF, false); v = v > t ? v : t;
  t = (unsigned)__builtin_amdgcn_update_dpp((int)v, (int)v, 0x122, 0xF, 0xF, false); v = v > t ? v : t;
  t = (unsigned)__builtin_amdgcn_update_dpp((int)v, (int)v, 0x124, 0xF, 0xF, false); v = v > t ? v : t;
  t = (unsigned)__builtin_amdgcn_update_dpp((int)v, (int)v, 0x128, 0xF, 0xF, false); v = v > t ? v : t;
  return v;
}
__device__ __forceinline__ int imin16(int v) {
  int t;
  t = __builtin_amdgcn_update_dpp(v, v, 0x121, 0xF, 0xF, false); v = v < t ? v : t;
  t = __builtin_amdgcn_update_dpp(v, v, 0x122, 0xF, 0xF, false); v = v < t ? v : t;
  t = __builtin_amdgcn_update_dpp(v, v, 0x124, 0xF, 0xF, false); v = v < t ? v : t;
  t = __builtin_amdgcn_update_dpp(v, v, 0x128, 0xF, 0xF, false); v = v < t ? v : t;
  return v;
}

// ---------------------------------------------------------------- zero
__global__ void zero_kernel(float* p, int n) {
  int i = blockIdx.x * blockDim.x + threadIdx.x;
  if (i < n) p[i] = 0.f;
}

// ---------------------------------------------------- weight prep (bf16)
__global__ void prep_weights(const float* __restrict__ pw_f, const float* __restrict__ mw_f,
                             const float* __restrict__ w0, const float* __restrict__ w1,
                             unsigned short* __restrict__ pw, unsigned short* __restrict__ mw,
                             unsigned short* __restrict__ w0t, unsigned short* __restrict__ w1t) {
  const int S1 = 512 * 256, S2 = 256 * 256, S3 = 512 * 512, S4 = 256 * 512;
  int i = blockIdx.x * 256 + threadIdx.x;
  if (i < S1) { pw[i] = f2bf(pw_f[i]); return; }
  i -= S1;
  if (i < S2) { mw[i] = f2bf(mw_f[i]); return; }
  i -= S2;
  if (i < S3) { int o = i >> 9, k = i & 511; w0t[i] = f2bf(w0[k * 512 + o]); return; }
  i -= S3;
  if (i < S4) { int o = i >> 9, k = i & 511; w1t[i] = f2bf(w1[k * 256 + o]); }
}

// ------------------------------------------- x: NCHW fp32 -> NHWC bf16
__global__ __launch_bounds__(256) void x_to_nhwc(const float* __restrict__ x,
                                                 unsigned short* __restrict__ xT) {
  __shared__ float tile[64][65];
  const int t = threadIdx.x;
  const int p0 = blockIdx.x * 64, c0 = blockIdx.y * 64, n = blockIdx.z;
#pragma unroll
  for (int i = 0; i < 4; i++) {
    const int c = i * 16 + (t >> 4);
    const float4 v = *(const float4*)(x + ((size_t)(n * 256 + c0 + c) << 14) + p0 + (t & 15) * 4);
    tile[c][(t & 15) * 4]     = v.x;
    tile[c][(t & 15) * 4 + 1] = v.y;
    tile[c][(t & 15) * 4 + 2] = v.z;
    tile[c][(t & 15) * 4 + 3] = v.w;
  }
  __syncthreads();
#pragma unroll
  for (int i = 0; i < 4; i++) {
    const int pp = i * 16 + (t >> 4);
    const int cl = (t & 15) * 4;
    us4 o;
    o.x = f2bf(tile[cl][pp]); o.y = f2bf(tile[cl + 1][pp]);
    o.z = f2bf(tile[cl + 2][pp]); o.w = f2bf(tile[cl + 3][pp]);
    *(us4*)&xT[(((size_t)n << 14) + p0 + pp) * 256 + c0 + cl] = o;
  }
}

// ---------------------------------------------------------- MFMA GEMM (v1, LDS)
// Y[n][p][o] = sum_k A[o][k] * B[n][p][k] + bias[o]  (optional gelu)
// __launch_bounds__(256,4): 4 blocks/CU (128KB LDS of 160), VGPR cap 128 (uses ~80).
template<bool CONCAT, bool GELU, bool STATS>
__global__ __launch_bounds__(256, 4) void mfma_gemm(
    const unsigned short* __restrict__ A, const float* __restrict__ bias,
    const unsigned short* __restrict__ B1, const unsigned short* __restrict__ B2,
    unsigned short* __restrict__ Y, int M, int K, int K1,
    int astride, int bstride, float* __restrict__ sums) {
  __shared__ unsigned short As[8192];
  __shared__ unsigned short Bs[8192];
  __shared__ float r1[4], r2[4];
  const int t = threadIdx.x;
  const int lane = t & 63, w = t >> 6;
  const int quad = lane >> 4, l16 = lane & 15;
  const int p0 = blockIdx.x * 128, m0 = blockIdx.y * 128;
  const int n = blockIdx.z;
  const int wm = w & 1, wn = w >> 1;
  const int K2 = K - K1;

  A += (size_t)n * astride;

  f32x4 acc[4][4];
#pragma unroll
  for (int im = 0; im < 4; im++)
#pragma unroll
    for (int in = 0; in < 4; in++) acc[im][in] = (f32x4)0.f;

  for (int k0 = 0; k0 < K; k0 += 64) {
    __syncthreads();
#pragma unroll
    for (int i = 0; i < 4; i++) {
      const int c = (w << 2) | i;
      const int tm = c >> 1, kk = c & 1;
      const int krow = k0 + kk * 32 + quad * 8;
      const unsigned short* ga = A + (size_t)(m0 + tm * 16 + l16) * K + krow;
      __builtin_amdgcn_global_load_lds((const __attribute__((address_space(1))) void*)ga,
          (__attribute__((address_space(3))) void*)&As[c * 512], 16, 0, 0);
      const int prow = p0 + tm * 16 + l16;
      const unsigned short* gb;
      if (!CONCAT || krow < K1)
        gb = B1 + ((((size_t)n << 14) + prow) * (size_t)K1) + krow;
      else
        gb = B2 + ((((size_t)n << 14) + prow) * (size_t)K2) + (krow - K1);
      __builtin_amdgcn_global_load_lds((const __attribute__((address_space(1))) void*)gb,
          (__attribute__((address_space(3))) void*)&Bs[c * 512], 16, 0, 0);
    }
    __syncthreads();
#pragma unroll
    for (int kk = 0; kk < 2; kk++) {
      short8 af[4], bfr[4];
#pragma unroll
      for (int im = 0; im < 4; im++)
        af[im] = *(const short8*)&As[(((wm * 4 + im) * 2 + kk) * 64 + lane) * 8];
#pragma unroll
      for (int in = 0; in < 4; in++)
        bfr[in] = *(const short8*)&Bs[(((wn * 4 + in) * 2 + kk) * 64 + lane) * 8];
#pragma unroll
      for (int im = 0; im < 4; im++)
#pragma unroll
        for (int in = 0; in < 4; in++)
          acc[im][in] = __builtin_amdgcn_mfma_f32_16x16x32_bf16(af[im], bfr[in], acc[im][in], 0, 0, 0);
    }
  }

  const size_t nb = ((size_t)n << 14);
  float s = 0.f, s2 = 0.f;
#pragma unroll
  for (int im = 0; im < 4; im++) {
    const int om = m0 + (wm * 4 + im) * 16 + quad * 4;
    const f32x4 bv = *(const f32x4*)(bias + (size_t)n * bstride + om);
#pragma unroll
    for (int in = 0; in < 4; in++) {
      const int p = p0 + (wn * 4 + in) * 16 + l16;
      float v0 = acc[im][in].x + bv.x;
      float v1 = acc[im][in].y + bv.y;
      float v2 = acc[im][in].z + bv.z;
      float v3 = acc[im][in].w + bv.w;
      if (GELU) { v0 = gelu_f(v0); v1 = gelu_f(v1); v2 = gelu_f(v2); v3 = gelu_f(v3); }
      if (STATS) {
        s += (v0 + v1) + (v2 + v3);
        s2 = fmaf(v0, v0, s2); s2 = fmaf(v1, v1, s2);
        s2 = fmaf(v2, v2, s2); s2 = fmaf(v3, v3, s2);
      }
      us4 o4;
      o4.x = f2bf(v0); o4.y = f2bf(v1); o4.z = f2bf(v2); o4.w = f2bf(v3);
      *(us4*)&Y[(nb + p) * M + om] = o4;
    }
  }
  if (STATS) {
#pragma unroll
    for (int off = 32; off > 0; off >>= 1) {
      s += __shfl_down(s, off);
      s2 += __shfl_down(s2, off);
    }
    if (lane == 0) { r1[w] = s; r2[w] = s2; }
    __syncthreads();
    if (t == 0) {
      atomicAdd(&sums[2 * n],     (r1[0] + r1[1]) + (r1[2] + r1[3]));
      atomicAdd(&sums[2 * n + 1], (r2[0] + r2[1]) + (r2[2] + r2[3]));
    }
  }
}

// ============================================================= CLUSTER
// m = 0..255 encodes n(3b) f(3b) s1 s2; region = 64x64 px, 64 ch at f*64.

// ---- A: per-8x8-block channel means -> cpnh_g (bf16 l2-normed point half),
//         cval_g (f32 value-half means). grid (slice4, m256), block 256.
__global__ __launch_bounds__(256) void centers_kernel(
    const unsigned short* __restrict__ y, unsigned short* __restrict__ cpnh_g,
    float* __restrict__ cval_g) {
  const int m = blockIdx.y, slice = blockIdx.x;
  const int n = m >> 5, f = (m >> 2) & 7, s1 = (m >> 1) & 1, s2 = m & 1;
  const int t = threadIdx.x;
  __shared__ float cs[16][68];

  const size_t nbase = ((size_t)n << 14);
  const int prow0 = s1 * 64, pcol0 = s2 * 64, ch0 = f * 64;

  {
    const int bl = t >> 4;                 // local block 0..15
    const int b = slice * 16 + bl;         // global block 0..63
    const int tid = t & 15, cg = tid & 7, ph = tid >> 3;
    const int pr0 = prow0 + (b >> 3) * 8 + ph * 4;
    const int pc0 = pcol0 + (b & 7) * 8;
    const unsigned short* yb = y + (nbase + (size_t)pr0 * 128 + pc0) * 512 + ch0 + cg * 8;
    float a8[8] = {0.f, 0.f, 0.f, 0.f, 0.f, 0.f, 0.f, 0.f};
#pragma unroll
    for (int r = 0; r < 4; r++) {
      us8 buf[8];
#pragma unroll
      for (int cc = 0; cc < 8; cc++)
        buf[cc] = *(const us8*)(yb + ((size_t)r * 128 + cc) * 512);
#pragma unroll
      for (int cc = 0; cc < 8; cc++)
#pragma unroll
        for (int j = 0; j < 8; j++) a8[j] += bf2f(buf[cc][j]);
    }
#pragma unroll
    for (int j = 0; j < 8; j++) a8[j] += __shfl_xor(a8[j], 8);
    if (ph == 0) {
      f32x4 o0, o1;
      o0.x = a8[0] * (1.f / 64.f); o0.y = a8[1] * (1.f / 64.f);
      o0.z = a8[2] * (1.f / 64.f); o0.w = a8[3] * (1.f / 64.f);
      o1.x = a8[4] * (1.f / 64.f); o1.y = a8[5] * (1.f / 64.f);
      o1.z = a8[6] * (1.f / 64.f); o1.w = a8[7] * (1.f / 64.f);
      *(f32x4*)&cs[bl][cg * 8]     = o0;
      *(f32x4*)&cs[bl][cg * 8 + 4] = o1;
    }
  }
  __syncthreads();

  if (t < 128) {
    const int bl = t >> 3, jg = t & 7;
    const int bg = slice * 16 + bl;
    if (jg < 8) {
      f32x4 ov;
      ov.x = cs[bl][32 + jg * 4]; ov.y = cs[bl][32 + jg * 4 + 1];
      ov.z = cs[bl][32 + jg * 4 + 2]; ov.w = cs[bl][32 + jg * 4 + 3];
      *(f32x4*)&cval_g[((size_t)(m * 64 + bg) << 5) + jg * 4] = ov;
    }
    float s = 0.f;
#pragma unroll
    for (int cc = 0; cc < 32; cc++) { const float v = cs[bl][cc]; s = fmaf(v, v, s); }
    const float inv = 1.f / fmaxf(sqrtf(s), 1e-12f);
    us4 o;
    o.x = f2bf(cs[bl][jg * 4] * inv);     o.y = f2bf(cs[bl][jg * 4 + 1] * inv);
    o.z = f2bf(cs[bl][jg * 4 + 2] * inv); o.w = f2bf(cs[bl][jg * 4 + 3] * inv);
    *(us4*)&cpnh_g[((size_t)(m * 64 + bg) << 5) + jg * 4] = o;
  }
}

// ---- B: assignment + partial value scatter. grid (slice8, m256), block 256.
// 8 tiles prefetched upfront; argmax fully VALU (mono-u32 DPP max + DPP min idx).
__global__ __launch_bounds__(256, 4) void assign_kernel(
    const unsigned short* __restrict__ y, const unsigned short* __restrict__ cpnh_g,
    const float* __restrict__ alpha_p, const float* __restrict__ beta_p,
    float* __restrict__ svals_g, unsigned char* __restrict__ sbest_g,
    float* __restrict__ accp_v, float* __restrict__ accp_c) {
  const int m = blockIdx.y, slice = blockIdx.x;
  const int n = m >> 5, f = (m >> 2) & 7, s1 = (m >> 1) & 1, s2 = m & 1;
  const int t = threadIdx.x;
  const int wave = t >> 6, lane = t & 63;
  const int quad = lane >> 4, l16 = lane & 15;
  const float alpha = alpha_p[0], beta = beta_p[0];

  __shared__ float accv[64][34];   // [b][0..31]=val acc, [32]=count

  for (int i = t; i < 64 * 34; i += 256) ((float*)accv)[i] = 0.f;

  const size_t nbase = ((size_t)n << 14);
  const int prow0 = s1 * 64, pcol0 = s2 * 64, ch0 = f * 64;

  const short8 cb0 = *(const short8*)&cpnh_g[((size_t)(m * 64 +  0 + l16) << 5) + quad * 8];
  const short8 cb1 = *(const short8*)&cpnh_g[((size_t)(m * 64 + 16 + l16) << 5) + quad * 8];
  const short8 cb2 = *(const short8*)&cpnh_g[((size_t)(m * 64 + 32 + l16) << 5) + quad * 8];
  const short8 cb3 = *(const short8*)&cpnh_g[((size_t)(m * 64 + 48 + l16) << 5) + quad * 8];
  const int sl4 = (((l16 >> 2) << 4) | (l16 & 3)) << 2;  // bpermute src addr
  __syncthreads();

  auto loadpt = [&](int tile, short8& a, short8& v) {
    const int pidx = slice * 512 + wave * 128 + tile * 16;
    const int pix = (prow0 + (pidx >> 6)) * 128 + pcol0 + (pidx & 63) + l16;
    const unsigned short* yp = y + (nbase + pix) * 512 + ch0 + quad * 8;
    a = *(const short8*)yp;         // point half frag
    v = *(const short8*)(yp + 32);  // value half
  };

  auto compute_tile = [&](int tile, short8 apt, short8 avl) {
    const int pidx = slice * 512 + wave * 128 + tile * 16;

    float nrm = 0.f;
#pragma unroll
    for (int j = 0; j < 8; j++) {
      const float fv = bf2f((unsigned short)apt[j]);
      nrm = fmaf(fv, fv, nrm);
    }
    nrm += __shfl_xor(nrm, 16);
    nrm += __shfl_xor(nrm, 32);
    const float inva = 1.f / fmaxf(sqrtf(nrm), 1e-12f);

    const f32x4 d0 = __builtin_amdgcn_mfma_f32_16x16x32_bf16(apt, cb0, (f32x4)0.f, 0, 0, 0);
    const f32x4 d1 = __builtin_amdgcn_mfma_f32_16x16x32_bf16(apt, cb1, (f32x4)0.f, 0, 0, 0);
    const f32x4 d2 = __builtin_amdgcn_mfma_f32_16x16x32_bf16(apt, cb2, (f32x4)0.f, 0, 0, 0);
    const f32x4 d3 = __builtin_amdgcn_mfma_f32_16x16x32_bf16(apt, cb3, (f32x4)0.f, 0, 0, 0);

    // per-row (point quad*4+r) exact argmax over 64 centers, all VALU:
    // monotonic-u32 fold + DPP rotate max; smallest idx among exact maxima
    // via cndmask + DPP rotate min. No ballots, no SALU round-trips.
    float bv[4]; int bi[4];
#pragma unroll
    for (int r = 0; r < 4; r++) {
      const unsigned u0 = fmono(d0[r]);
      const unsigned u1 = fmono(d1[r]);
      const unsigned u2 = fmono(d2[r]);
      const unsigned u3 = fmono(d3[r]);
      unsigned mx = u0 > u1 ? u0 : u1;
      const unsigned mxb = u2 > u3 ? u2 : u3;
      mx = mx > mxb ? mx : mxb;
      mx = umax16(mx);
      int c0 = (u0 == mx) ? l16        : 64;
      int c1 = (u1 == mx) ? (16 + l16) : 64;
      int c2 = (u2 == mx) ? (32 + l16) : 64;
      int c3 = (u3 == mx) ? (48 + l16) : 64;
      int ci = c0 < c1 ? c0 : c1;
      const int cb = c2 < c3 ? c2 : c3;
      ci = ci < cb ? ci : cb;
      ci = imin16(ci);
      bi[r] = ci;
      bv[r] = __uint_as_float((mx & 0x80000000u) ? (mx ^ 0x80000000u) : ~mx);
    }

    // redistribute: lane takes row l16 from lane ((l16>>2)*16 + (l16&3)).
    // pack idx into low 6 mantissa bits of the dot -> single bpermute.
    const float rv01 = (l16 & 1) ? bv[1] : bv[0];
    const float rv23 = (l16 & 1) ? bv[3] : bv[2];
    const float rowv = (l16 & 2) ? rv23 : rv01;
    const int   ri01 = (l16 & 1) ? bi[1] : bi[0];
    const int   ri23 = (l16 & 1) ? bi[3] : bi[2];
    const int   rowi = (l16 & 2) ? ri23 : ri01;
    const unsigned pk = (__float_as_uint(rowv) & ~63u) | (unsigned)rowi;
    const unsigned got = (unsigned)__builtin_amdgcn_ds_bpermute(sl4, (int)pk);
    const int   idx = (int)(got & 63u);
    const float dot = __uint_as_float(got & ~63u);

    const float val = 1.f / (1.f + __expf(-fmaf(alpha, dot * inva, beta)));
    if (quad == 0) {
      svals_g[(size_t)m * 4096 + pidx + l16] = val;
      sbest_g[(size_t)m * 4096 + pidx + l16] = (unsigned char)idx;
    }
#pragma unroll
    for (int j = 0; j < 8; j++)
      atomicAdd(&accv[idx][quad * 8 + j], val * bf2f((unsigned short)avl[j]));
    if (quad == 0) atomicAdd(&accv[idx][32], val);
  };

  {
    short8 a0, v0, a1, v1, a2, v2, a3, v3, a4, v4, a5, v5, a6, v6, a7, v7;
    loadpt(0, a0, v0); loadpt(1, a1, v1); loadpt(2, a2, v2); loadpt(3, a3, v3);
    loadpt(4, a4, v4); loadpt(5, a5, v5); loadpt(6, a6, v6); loadpt(7, a7, v7);
    compute_tile(0, a0, v0); compute_tile(1, a1, v1);
    compute_tile(2, a2, v2); compute_tile(3, a3, v3);
    compute_tile(4, a4, v4); compute_tile(5, a5, v5);
    compute_tile(6, a6, v6); compute_tile(7, a7, v7);
  }
  __syncthreads();

  const size_t pb = ((size_t)(m * 8 + slice)) * 64;
  for (int i = t; i < 2048; i += 256) {
    const int b = i >> 5, q = i & 31;
    accp_v[(pb + b) * 32 + q] = accv[b][q];
  }
  if (t < 64) accp_c[pb + t] = accv[t][32];
}

// ---- D: reduce partial means + gather -> nx. grid (slice8, m256), block 256.
__global__ __launch_bounds__(256) void gather_kernel(
    const float* __restrict__ accp_v, const float* __restrict__ accp_c,
    const float* __restrict__ cval_g, const float* __restrict__ svals_g,
    const unsigned char* __restrict__ sbest_g, unsigned short* __restrict__ nx) {
  const int m = blockIdx.y, slice = blockIdx.x;
  const int n = m >> 5, f = (m >> 2) & 7, s1 = (m >> 1) & 1, s2 = m & 1;
  const int t = threadIdx.x;
  __shared__ float cm[64][34];

  const size_t nbase = ((size_t)n << 14);
  const int prow0 = s1 * 64, pcol0 = s2 * 64;

  for (int i = t; i < 2048; i += 256) {
    const int b = i >> 5, q = i & 31;
    float s = cval_g[((size_t)(m * 64 + b) << 5) + q];
    float c = 1.f;
#pragma unroll
    for (int s8 = 0; s8 < 8; s8++) {
      const size_t pb = ((size_t)(m * 8 + s8)) * 64 + b;
      s += accp_v[pb * 32 + q];
      c += accp_c[pb];
    }
    cm[b][q] = s / c;
  }
  __syncthreads();

#pragma unroll
  for (int pass = 0; pass < 2; pass++) {
    const int l = slice * 512 + pass * 256 + t;
    const int p = (prow0 + (l >> 6)) * 128 + pcol0 + (l & 63);
    const float v = svals_g[(size_t)m * 4096 + l];
    const int b = sbest_g[(size_t)m * 4096 + l];
    unsigned short* nr = nx + (nbase + p) * 256 + f * 32;
#pragma unroll
    for (int q8 = 0; q8 < 4; q8++) {
      const float2 a0 = *(const float2*)&cm[b][q8 * 8];
      const float2 a1 = *(const float2*)&cm[b][q8 * 8 + 2];
      const float2 a2 = *(const float2*)&cm[b][q8 * 8 + 4];
      const float2 a3 = *(const float2*)&cm[b][q8 * 8 + 6];
      us8 o;
      o[0] = f2bf(v * a0.x); o[1] = f2bf(v * a0.y);
      o[2] = f2bf(v * a1.x); o[3] = f2bf(v * a1.y);
      o[4] = f2bf(v * a2.x); o[5] = f2bf(v * a2.y);
      o[6] = f2bf(v * a3.x); o[7] = f2bf(v * a3.y);
      *(us8*)&nr[q8 * 8] = o;
    }
  }
}

// ---------------- GN0 per-(n,c) affine coefficients from fused sums
__global__ void gn_finalize0(const float* __restrict__ sums, const float* __restrict__ g0w,
                             const float* __restrict__ g0b, float* __restrict__ scl,
                             float* __restrict__ bia) {
  const int n = blockIdx.x, c = threadIdx.x;
  const float cntinv = 1.f / (float)(CIN * PIX);
  const float mu = sums[2 * n] * cntinv;
  const float var = sums[2 * n + 1] * cntinv - mu * mu;
  const float rs = rsqrtf(var + 1e-5f);
  const float a = rs * g0w[c];
  scl[n * 256 + c] = a;
  bia[n * 256 + c] = g0b[c] - mu * a;
}

// ---------------- fold GN0 scale into MLP0 weights (per image)
__global__ void w0_scale(const unsigned short* __restrict__ w0t,
                         const float* __restrict__ scl, unsigned short* __restrict__ w0s) {
  const int n = blockIdx.y;
  const int i = blockIdx.x * 256 + threadIdx.x;   // 0..262143
  const int k = i & 511;
  unsigned short v = w0t[i];
  if (k >= 256) v = f2bf(bf2f(v) * scl[n * 256 + k - 256]);
  w0s[(size_t)n * 262144 + i] = v;
}

// ---------------- effective MLP0 bias: b0e[n][o] = b0[o] + sum_k W0n[o][k]*bia[n][k]
__global__ void b0_eff(const unsigned short* __restrict__ w0t, const float* __restrict__ b0,
                       const float* __restrict__ bia, float* __restrict__ b0e) {
  const int n = blockIdx.y;
  const int o = blockIdx.x * 256 + threadIdx.x;   // 0..511
  float s = b0[o];
  const unsigned short* wr = w0t + (size_t)o * 512 + 256;
  const float* br = bia + n * 256;
#pragma unroll 4
  for (int k = 0; k < 256; k++) s = fmaf(bf2f(wr[k]), br[k], s);
  b0e[n * 512 + o] = s;
}

// ------------------- final: GN1 affine + layer_scale + residual, NHWC->NCHW
__global__ __launch_bounds__(256) void final_transpose(
    const unsigned short* __restrict__ u, const float* __restrict__ x,
    const float* __restrict__ sums, const float* __restrict__ g1w,
    const float* __restrict__ g1b, const float* __restrict__ lsc,
    float* __restrict__ out) {
  __shared__ float tile[64][68];
  const int t = threadIdx.x;
  const int p0 = blockIdx.x * 64, c0 = blockIdx.y * 64, n = blockIdx.z;
  {
    const int pl = t >> 2, g = t & 3;
    const unsigned short* up = u + ((((size_t)n << 14) + p0 + pl) << 8) + c0 + g * 16;
    const us8 v0 = *(const us8*)up;
    const us8 v1 = *(const us8*)(up + 8);
#pragma unroll
    for (int j = 0; j < 8; j++) {
      tile[pl][g * 16 + j] = bf2f(v0[j]);
      tile[pl][g * 16 + 8 + j] = bf2f(v1[j]);
    }
  }
  __syncthreads();
  {
    const int cl = t >> 2, g = t & 3;
    const int c = c0 + cl;
    const float cntinv = 1.f / (float)(CIN * PIX);
    const float mu = sums[2 * n] * cntinv;
    const float var = sums[2 * n + 1] * cntinv - mu * mu;
    const float rs = rsqrtf(var + 1e-5f);
    const float gw = rs * g1w[c] * lsc[c];
    const float gb = (g1b[c] - mu * rs * g1w[c]) * lsc[c];
    const size_t rowb = ((size_t)(n * 256 + c) << 14) + p0 + g * 16;
#pragma unroll
    for (int q = 0; q < 4; q++) {
      const float4 xv = *(const float4*)(x + rowb + q * 4);
      float4 o;
      o.x = fmaf(tile[g * 16 + q * 4][cl], gw, gb) + xv.x;
      o.y = fmaf(tile[g * 16 + q * 4 + 1][cl], gw, gb) + xv.y;
      o.z = fmaf(tile[g * 16 + q * 4 + 2][cl], gw, gb) + xv.z;
      o.w = fmaf(tile[g * 16 + q * 4 + 3][cl], gw, gb) + xv.w;
      *(float4*)(out + rowb + q * 4) = o;
    }
  }
}

// ---------------------------------------------------------------- launch
extern "C" void kernel_launch(void* const* d_in, const int* in_sizes, int n_in,
                              void* d_out, int out_size, void* d_ws, size_t ws_size,
                              hipStream_t stream) {
  const float* x       = (const float*)d_in[0];
  const float* proj_w  = (const float*)d_in[1];
  const float* proj_b  = (const float*)d_in[2];
  const float* merge_w = (const float*)d_in[3];
  const float* merge_b = (const float*)d_in[4];
  const float* alpha   = (const float*)d_in[5];
  const float* beta    = (const float*)d_in[6];
  const float* g0w     = (const float*)d_in[7];
  const float* g0b     = (const float*)d_in[8];
  const float* w0      = (const float*)d_in[9];
  const float* b0      = (const float*)d_in[10];
  const float* w1      = (const float*)d_in[11];
  const float* b1      = (const float*)d_in[12];
  const float* g1w     = (const float*)d_in[13];
  const float* g1b     = (const float*)d_in[14];
  const float* lsc     = (const float*)d_in[15];
  float* out = (float*)d_out;

  // workspace (ushort units), ~274 MB; newx + cluster scratch live in d_out
  unsigned short* wsu = (unsigned short*)d_ws;
  unsigned short* xT  = wsu;                      // 8*16384*256
  unsigned short* y   = xT + (size_t)33554432;    // 8*16384*512 (reused as h)
  unsigned short* nx  = y + (size_t)67108864;     // 8*16384*256 (reused as u)
  unsigned short* pw  = nx + (size_t)33554432;    // 512*256
  unsigned short* mw  = pw + 131072;              // 256*256
  unsigned short* w0t = mw + 65536;               // 512*512
  unsigned short* w1t = w0t + 262144;             // 256*512
  unsigned short* w0s = w1t + 131072;             // 8*512*512
  float* sums = (float*)(w0s + (size_t)2097152);  // 32
  float* scl0 = sums + 32;                        // 8*256
  float* bia0 = scl0 + 2048;                      // 8*256
  float* b0e  = bia0 + 2048;                      // 8*512
  unsigned short* newx = (unsigned short*)d_out;  // scratch inside out (64MB)

  // cluster scratch in the upper half of d_out (dead before final_transpose)
  float* svals_g = (float*)((char*)d_out + 67108864);       // 256*4096 f32 (4MB)
  float* cval_g  = svals_g + 1048576;                       // 256*64*32 f32 (2MB)
  float* accp_v  = cval_g + 524288;                         // 256*8*64*32 f32 (16.8MB)
  float* accp_c  = accp_v + 4194304;                        // 256*8*64 f32 (0.5MB)
  unsigned short* cpnh_g = (unsigned short*)(accp_c + 131072);  // 256*64*32 bf16 (1MB)
  unsigned char*  sbest_g = (unsigned char*)(cpnh_g + 524288);  // 256*4096 u8 (1MB)

  zero_kernel<<<1, 64, 0, stream>>>(sums, 32);
  prep_weights<<<2304, 256, 0, stream>>>(proj_w, merge_w, w0, w1, pw, mw, w0t, w1t);
  x_to_nhwc<<<dim3(256, 4, NB), 256, 0, stream>>>(x, xT);

  // proj: y[n][p][512] = pw @ xT
  mfma_gemm<false, false, false><<<dim3(128, 4, NB), 256, 0, stream>>>(
      pw, proj_b, xT, nullptr, y, 512, 256, 256, 0, 0, nullptr);

  // cluster (split)
  centers_kernel<<<dim3(4, 256), 256, 0, stream>>>(y, cpnh_g, cval_g);
  assign_kernel<<<dim3(8, 256), 256, 0, stream>>>(
      y, cpnh_g, alpha, beta, svals_g, sbest_g, accp_v, accp_c);
  gather_kernel<<<dim3(8, 256), 256, 0, stream>>>(
      accp_v, accp_c, cval_g, svals_g, sbest_g, nx);

  // merge: newx = mw @ nx, fused GN0 stats -> sums[0..15]
  mfma_gemm<false, false, true><<<dim3(128, 2, NB), 256, 0, stream>>>(
      mw, merge_b, nx, nullptr, newx, 256, 256, 256, 0, 0, sums);

  // GN0 affine coefficients, folded weights & bias
  gn_finalize0<<<NB, 256, 0, stream>>>(sums, g0w, g0b, scl0, bia0);
  w0_scale<<<dim3(1024, NB), 256, 0, stream>>>(w0t, scl0, w0s);
  b0_eff<<<dim3(2, NB), 256, 0, stream>>>(w0t, b0, bia0, b0e);

  // MLP0: h = gelu(w0s_n @ [xT ; newx] + b0e_n)   (h reuses y)
  mfma_gemm<true, true, false><<<dim3(128, 4, NB), 256, 0, stream>>>(
      w0s, b0e, xT, newx, y, 512, 512, 256, 262144, 512, nullptr);

  // MLP1: u = w1t @ h + b1, fused GN1 stats -> sums[16..31]   (u reuses nx)
  mfma_gemm<false, false, true><<<dim3(128, 2, NB), 256, 0, stream>>>(
      w1t, b1, y, nullptr, nx, 256, 512, 512, 0, 0, sums + 16);

  // final transpose/residual
  final_transpose<<<dim3(256, 4, NB), 256, 0, stream>>>(
      nx, x, sums + 16, g1w, g1b, lsc, out);
}

// Round 8
// 915.435 us; speedup vs baseline: 1.3078x; 1.0954x over previous
//
#include <hip/hip_runtime.h>
#include <math.h>

#define PIX   16384       // H*W
#define NB    8
#define CIN   256

typedef __attribute__((ext_vector_type(8))) short    short8;   // bf16x8 frag (4 VGPR)
typedef __attribute__((ext_vector_type(4))) float    f32x4;
typedef __attribute__((ext_vector_type(4))) unsigned short us4;
typedef __attribute__((ext_vector_type(8))) unsigned short us8;
typedef __attribute__((ext_vector_type(4))) unsigned char uc4;

__device__ __forceinline__ float bf2f(unsigned short h) {
  return __uint_as_float(((unsigned int)h) << 16);
}
__device__ __forceinline__ unsigned short f2bf(float f) {  // round-nearest-even
  unsigned int u = __float_as_uint(f);
  return (unsigned short)((u + 0x7FFFu + ((u >> 16) & 1u)) >> 16);
}
__device__ __forceinline__ float gelu_f(float v) {
  return 0.5f * v * (1.f + erff(v * 0.70710678118654752f));
}

// order-preserving f32 -> u32 map (unsigned compare == float compare)
__device__ __forceinline__ unsigned fmono(float f) {
  const unsigned u = __float_as_uint(f);
  return (u & 0x80000000u) ? ~u : (u | 0x80000000u);
}

// max/min over the 16 lanes of each DPP row — pure VALU rotate-reduce
__device__ __forceinline__ unsigned umax16(unsigned v) {
  unsigned t;
  t = (unsigned)__builtin_amdgcn_update_dpp((int)v, (int)v, 0x121, 0xF, 0xF, false); v = v > t ? v : t;
  t = (unsigned)__builtin_amdgcn_update_dpp((int)v, (int)v, 0x122, 0xF, 0xF, false); v = v > t ? v : t;
  t = (unsigned)__builtin_amdgcn_update_dpp((int)v, (int)v, 0x124, 0xF, 0xF, false); v = v > t ? v : t;
  t = (unsigned)__builtin_amdgcn_update_dpp((int)v, (int)v, 0x128, 0xF, 0xF, false); v = v > t ? v : t;
  return v;
}
__device__ __forceinline__ int imin16(int v) {
  int t;
  t = __builtin_amdgcn_update_dpp(v, v, 0x121, 0xF, 0xF, false); v = v < t ? v : t;
  t = __builtin_amdgcn_update_dpp(v, v, 0x122, 0xF, 0xF, false); v = v < t ? v : t;
  t = __builtin_amdgcn_update_dpp(v, v, 0x124, 0xF, 0xF, false); v = v < t ? v : t;
  t = __builtin_amdgcn_update_dpp(v, v, 0x128, 0xF, 0xF, false); v = v < t ? v : t;
  return v;
}

// ---------------------------------------------------------------- zero
__global__ void zero_kernel(float* p, int n) {
  int i = blockIdx.x * blockDim.x + threadIdx.x;
  if (i < n) p[i] = 0.f;
}

// ---------------------------------------------------- weight prep (bf16)
__global__ void prep_weights(const float* __restrict__ pw_f, const float* __restrict__ mw_f,
                             const float* __restrict__ w0, const float* __restrict__ w1,
                             unsigned short* __restrict__ pw, unsigned short* __restrict__ mw,
                             unsigned short* __restrict__ w0t, unsigned short* __restrict__ w1t) {
  const int S1 = 512 * 256, S2 = 256 * 256, S3 = 512 * 512, S4 = 256 * 512;
  int i = blockIdx.x * 256 + threadIdx.x;
  if (i < S1) { pw[i] = f2bf(pw_f[i]); return; }
  i -= S1;
  if (i < S2) { mw[i] = f2bf(mw_f[i]); return; }
  i -= S2;
  if (i < S3) { int o = i >> 9, k = i & 511; w0t[i] = f2bf(w0[k * 512 + o]); return; }
  i -= S3;
  if (i < S4) { int o = i >> 9, k = i & 511; w1t[i] = f2bf(w1[k * 256 + o]); }
}

// ------------------------------------------- x: NCHW fp32 -> NHWC bf16
__global__ __launch_bounds__(256) void x_to_nhwc(const float* __restrict__ x,
                                                 unsigned short* __restrict__ xT) {
  __shared__ float tile[64][65];
  const int t = threadIdx.x;
  const int p0 = blockIdx.x * 64, c0 = blockIdx.y * 64, n = blockIdx.z;
#pragma unroll
  for (int i = 0; i < 4; i++) {
    const int c = i * 16 + (t >> 4);
    const float4 v = *(const float4*)(x + ((size_t)(n * 256 + c0 + c) << 14) + p0 + (t & 15) * 4);
    tile[c][(t & 15) * 4]     = v.x;
    tile[c][(t & 15) * 4 + 1] = v.y;
    tile[c][(t & 15) * 4 + 2] = v.z;
    tile[c][(t & 15) * 4 + 3] = v.w;
  }
  __syncthreads();
#pragma unroll
  for (int i = 0; i < 4; i++) {
    const int pp = i * 16 + (t >> 4);
    const int cl = (t & 15) * 4;
    us4 o;
    o.x = f2bf(tile[cl][pp]); o.y = f2bf(tile[cl + 1][pp]);
    o.z = f2bf(tile[cl + 2][pp]); o.w = f2bf(tile[cl + 3][pp]);
    *(us4*)&xT[(((size_t)n << 14) + p0 + pp) * 256 + c0 + cl] = o;
  }
}

// ---------------------------------------------------------- MFMA GEMM (v1, LDS)
// __launch_bounds__(256,4): 4 blocks/CU (128KB LDS of 160), VGPR cap 128 (uses ~80).
template<bool CONCAT, bool GELU, bool STATS>
__global__ __launch_bounds__(256, 4) void mfma_gemm(
    const unsigned short* __restrict__ A, const float* __restrict__ bias,
    const unsigned short* __restrict__ B1, const unsigned short* __restrict__ B2,
    unsigned short* __restrict__ Y, int M, int K, int K1,
    int astride, int bstride, float* __restrict__ sums) {
  __shared__ unsigned short As[8192];
  __shared__ unsigned short Bs[8192];
  __shared__ float r1[4], r2[4];
  const int t = threadIdx.x;
  const int lane = t & 63, w = t >> 6;
  const int quad = lane >> 4, l16 = lane & 15;
  const int p0 = blockIdx.x * 128, m0 = blockIdx.y * 128;
  const int n = blockIdx.z;
  const int wm = w & 1, wn = w >> 1;
  const int K2 = K - K1;

  A += (size_t)n * astride;

  f32x4 acc[4][4];
#pragma unroll
  for (int im = 0; im < 4; im++)
#pragma unroll
    for (int in = 0; in < 4; in++) acc[im][in] = (f32x4)0.f;

  for (int k0 = 0; k0 < K; k0 += 64) {
    __syncthreads();
#pragma unroll
    for (int i = 0; i < 4; i++) {
      const int c = (w << 2) | i;
      const int tm = c >> 1, kk = c & 1;
      const int krow = k0 + kk * 32 + quad * 8;
      const unsigned short* ga = A + (size_t)(m0 + tm * 16 + l16) * K + krow;
      __builtin_amdgcn_global_load_lds((const __attribute__((address_space(1))) void*)ga,
          (__attribute__((address_space(3))) void*)&As[c * 512], 16, 0, 0);
      const int prow = p0 + tm * 16 + l16;
      const unsigned short* gb;
      if (!CONCAT || krow < K1)
        gb = B1 + ((((size_t)n << 14) + prow) * (size_t)K1) + krow;
      else
        gb = B2 + ((((size_t)n << 14) + prow) * (size_t)K2) + (krow - K1);
      __builtin_amdgcn_global_load_lds((const __attribute__((address_space(1))) void*)gb,
          (__attribute__((address_space(3))) void*)&Bs[c * 512], 16, 0, 0);
    }
    __syncthreads();
#pragma unroll
    for (int kk = 0; kk < 2; kk++) {
      short8 af[4], bfr[4];
#pragma unroll
      for (int im = 0; im < 4; im++)
        af[im] = *(const short8*)&As[(((wm * 4 + im) * 2 + kk) * 64 + lane) * 8];
#pragma unroll
      for (int in = 0; in < 4; in++)
        bfr[in] = *(const short8*)&Bs[(((wn * 4 + in) * 2 + kk) * 64 + lane) * 8];
#pragma unroll
      for (int im = 0; im < 4; im++)
#pragma unroll
        for (int in = 0; in < 4; in++)
          acc[im][in] = __builtin_amdgcn_mfma_f32_16x16x32_bf16(af[im], bfr[in], acc[im][in], 0, 0, 0);
    }
  }

  const size_t nb = ((size_t)n << 14);
  float s = 0.f, s2 = 0.f;
#pragma unroll
  for (int im = 0; im < 4; im++) {
    const int om = m0 + (wm * 4 + im) * 16 + quad * 4;
    const f32x4 bv = *(const f32x4*)(bias + (size_t)n * bstride + om);
#pragma unroll
    for (int in = 0; in < 4; in++) {
      const int p = p0 + (wn * 4 + in) * 16 + l16;
      float v0 = acc[im][in].x + bv.x;
      float v1 = acc[im][in].y + bv.y;
      float v2 = acc[im][in].z + bv.z;
      float v3 = acc[im][in].w + bv.w;
      if (GELU) { v0 = gelu_f(v0); v1 = gelu_f(v1); v2 = gelu_f(v2); v3 = gelu_f(v3); }
      if (STATS) {
        s += (v0 + v1) + (v2 + v3);
        s2 = fmaf(v0, v0, s2); s2 = fmaf(v1, v1, s2);
        s2 = fmaf(v2, v2, s2); s2 = fmaf(v3, v3, s2);
      }
      us4 o4;
      o4.x = f2bf(v0); o4.y = f2bf(v1); o4.z = f2bf(v2); o4.w = f2bf(v3);
      *(us4*)&Y[(nb + p) * M + om] = o4;
    }
  }
  if (STATS) {
#pragma unroll
    for (int off = 32; off > 0; off >>= 1) {
      s += __shfl_down(s, off);
      s2 += __shfl_down(s2, off);
    }
    if (lane == 0) { r1[w] = s; r2[w] = s2; }
    __syncthreads();
    if (t == 0) {
      atomicAdd(&sums[2 * n],     (r1[0] + r1[1]) + (r1[2] + r1[3]));
      atomicAdd(&sums[2 * n + 1], (r2[0] + r2[1]) + (r2[2] + r2[3]));
    }
  }
}

// ============================================================= CLUSTER
// m = 0..255 encodes n(3b) f(3b) s1 s2; region = 64x64 px, 64 ch at f*64.

// ---- A: per-8x8-block channel means -> cpnh_g (bf16 l2-normed point half),
//         cval_g (f32 value-half means). grid (slice4, m256), block 256.
__global__ __launch_bounds__(256) void centers_kernel(
    const unsigned short* __restrict__ y, unsigned short* __restrict__ cpnh_g,
    float* __restrict__ cval_g) {
  const int m = blockIdx.y, slice = blockIdx.x;
  const int n = m >> 5, f = (m >> 2) & 7, s1 = (m >> 1) & 1, s2 = m & 1;
  const int t = threadIdx.x;
  __shared__ float cs[16][68];

  const size_t nbase = ((size_t)n << 14);
  const int prow0 = s1 * 64, pcol0 = s2 * 64, ch0 = f * 64;

  {
    const int bl = t >> 4;                 // local block 0..15
    const int b = slice * 16 + bl;         // global block 0..63
    const int tid = t & 15, cg = tid & 7, ph = tid >> 3;
    const int pr0 = prow0 + (b >> 3) * 8 + ph * 4;
    const int pc0 = pcol0 + (b & 7) * 8;
    const unsigned short* yb = y + (nbase + (size_t)pr0 * 128 + pc0) * 512 + ch0 + cg * 8;
    float a8[8] = {0.f, 0.f, 0.f, 0.f, 0.f, 0.f, 0.f, 0.f};
#pragma unroll
    for (int r = 0; r < 4; r++) {
      us8 buf[8];
#pragma unroll
      for (int cc = 0; cc < 8; cc++)
        buf[cc] = *(const us8*)(yb + ((size_t)r * 128 + cc) * 512);
#pragma unroll
      for (int cc = 0; cc < 8; cc++)
#pragma unroll
        for (int j = 0; j < 8; j++) a8[j] += bf2f(buf[cc][j]);
    }
#pragma unroll
    for (int j = 0; j < 8; j++) a8[j] += __shfl_xor(a8[j], 8);
    if (ph == 0) {
      f32x4 o0, o1;
      o0.x = a8[0] * (1.f / 64.f); o0.y = a8[1] * (1.f / 64.f);
      o0.z = a8[2] * (1.f / 64.f); o0.w = a8[3] * (1.f / 64.f);
      o1.x = a8[4] * (1.f / 64.f); o1.y = a8[5] * (1.f / 64.f);
      o1.z = a8[6] * (1.f / 64.f); o1.w = a8[7] * (1.f / 64.f);
      *(f32x4*)&cs[bl][cg * 8]     = o0;
      *(f32x4*)&cs[bl][cg * 8 + 4] = o1;
    }
  }
  __syncthreads();

  if (t < 128) {
    const int bl = t >> 3, jg = t & 7;
    const int bg = slice * 16 + bl;
    if (jg < 8) {
      f32x4 ov;
      ov.x = cs[bl][32 + jg * 4]; ov.y = cs[bl][32 + jg * 4 + 1];
      ov.z = cs[bl][32 + jg * 4 + 2]; ov.w = cs[bl][32 + jg * 4 + 3];
      *(f32x4*)&cval_g[((size_t)(m * 64 + bg) << 5) + jg * 4] = ov;
    }
    float s = 0.f;
#pragma unroll
    for (int cc = 0; cc < 32; cc++) { const float v = cs[bl][cc]; s = fmaf(v, v, s); }
    const float inv = 1.f / fmaxf(sqrtf(s), 1e-12f);
    us4 o;
    o.x = f2bf(cs[bl][jg * 4] * inv);     o.y = f2bf(cs[bl][jg * 4 + 1] * inv);
    o.z = f2bf(cs[bl][jg * 4 + 2] * inv); o.w = f2bf(cs[bl][jg * 4 + 3] * inv);
    *(us4*)&cpnh_g[((size_t)(m * 64 + bg) << 5) + jg * 4] = o;
  }
}

// ---- B: assignment + partial value reduction. grid (slice8, m256), block 256.
// Phase A: MFMA sim + VALU argmax + sigmoid; per-point results stored to LDS
// (NO atomics — LDS atomic RMW retires ~1 lane/cy, was the 190us binder).
// Phase B: atomic-free conditional scan; thread (b=t>>2, g=t&3) accumulates
// val*value for points with idx==b into registers, writes partials directly.
__global__ __launch_bounds__(256, 4) void assign_kernel(
    const unsigned short* __restrict__ y, const unsigned short* __restrict__ cpnh_g,
    const float* __restrict__ alpha_p, const float* __restrict__ beta_p,
    float* __restrict__ svals_g, unsigned char* __restrict__ sbest_g,
    float* __restrict__ accp_v, float* __restrict__ accp_c) {
  const int m = blockIdx.y, slice = blockIdx.x;
  const int n = m >> 5, f = (m >> 2) & 7, s1 = (m >> 1) & 1, s2 = m & 1;
  const int t = threadIdx.x;
  const int wave = t >> 6, lane = t & 63;
  const int quad = lane >> 4, l16 = lane & 15;
  const float alpha = alpha_p[0], beta = beta_p[0];

  __shared__ unsigned short yvs[512][34];   // value halves (row-padded, bank-clean)
  __shared__ float svalss[512];             // per-point sigmoid val
  __shared__ unsigned char sidxs[512];      // per-point best center

  const size_t nbase = ((size_t)n << 14);
  const int prow0 = s1 * 64, pcol0 = s2 * 64, ch0 = f * 64;

  const short8 cb0 = *(const short8*)&cpnh_g[((size_t)(m * 64 +  0 + l16) << 5) + quad * 8];
  const short8 cb1 = *(const short8*)&cpnh_g[((size_t)(m * 64 + 16 + l16) << 5) + quad * 8];
  const short8 cb2 = *(const short8*)&cpnh_g[((size_t)(m * 64 + 32 + l16) << 5) + quad * 8];
  const short8 cb3 = *(const short8*)&cpnh_g[((size_t)(m * 64 + 48 + l16) << 5) + quad * 8];
  const int sl4 = (((l16 >> 2) << 4) | (l16 & 3)) << 2;  // bpermute src addr

  auto loadpt = [&](int tile, short8& a, short8& v) {
    const int pidx = slice * 512 + wave * 128 + tile * 16;
    const int pix = (prow0 + (pidx >> 6)) * 128 + pcol0 + (pidx & 63) + l16;
    const unsigned short* yp = y + (nbase + pix) * 512 + ch0 + quad * 8;
    a = *(const short8*)yp;         // point half frag
    v = *(const short8*)(yp + 32);  // value half
  };

  auto compute_tile = [&](int tile, short8 apt, short8 avl) {
    const int pl = wave * 128 + tile * 16 + l16;   // block-local point 0..511
    const int pidx = slice * 512 + pl;

    float nrm = 0.f;
#pragma unroll
    for (int j = 0; j < 8; j++) {
      const float fv = bf2f((unsigned short)apt[j]);
      nrm = fmaf(fv, fv, nrm);
    }
    nrm += __shfl_xor(nrm, 16);
    nrm += __shfl_xor(nrm, 32);
    const float inva = 1.f / fmaxf(sqrtf(nrm), 1e-12f);

    const f32x4 d0 = __builtin_amdgcn_mfma_f32_16x16x32_bf16(apt, cb0, (f32x4)0.f, 0, 0, 0);
    const f32x4 d1 = __builtin_amdgcn_mfma_f32_16x16x32_bf16(apt, cb1, (f32x4)0.f, 0, 0, 0);
    const f32x4 d2 = __builtin_amdgcn_mfma_f32_16x16x32_bf16(apt, cb2, (f32x4)0.f, 0, 0, 0);
    const f32x4 d3 = __builtin_amdgcn_mfma_f32_16x16x32_bf16(apt, cb3, (f32x4)0.f, 0, 0, 0);

    // per-row exact argmax over 64 centers, all VALU
    float bv[4]; int bi[4];
#pragma unroll
    for (int r = 0; r < 4; r++) {
      const unsigned u0 = fmono(d0[r]);
      const unsigned u1 = fmono(d1[r]);
      const unsigned u2 = fmono(d2[r]);
      const unsigned u3 = fmono(d3[r]);
      unsigned mx = u0 > u1 ? u0 : u1;
      const unsigned mxb = u2 > u3 ? u2 : u3;
      mx = mx > mxb ? mx : mxb;
      mx = umax16(mx);
      int c0 = (u0 == mx) ? l16        : 64;
      int c1 = (u1 == mx) ? (16 + l16) : 64;
      int c2 = (u2 == mx) ? (32 + l16) : 64;
      int c3 = (u3 == mx) ? (48 + l16) : 64;
      int ci = c0 < c1 ? c0 : c1;
      const int cb = c2 < c3 ? c2 : c3;
      ci = ci < cb ? ci : cb;
      ci = imin16(ci);
      bi[r] = ci;
      bv[r] = __uint_as_float((mx & 0x80000000u) ? (mx ^ 0x80000000u) : ~mx);
    }

    // redistribute rows -> lanes; pack idx into low 6 mantissa bits, 1 bpermute
    const float rv01 = (l16 & 1) ? bv[1] : bv[0];
    const float rv23 = (l16 & 1) ? bv[3] : bv[2];
    const float rowv = (l16 & 2) ? rv23 : rv01;
    const int   ri01 = (l16 & 1) ? bi[1] : bi[0];
    const int   ri23 = (l16 & 1) ? bi[3] : bi[2];
    const int   rowi = (l16 & 2) ? ri23 : ri01;
    const unsigned pk = (__float_as_uint(rowv) & ~63u) | (unsigned)rowi;
    const unsigned got = (unsigned)__builtin_amdgcn_ds_bpermute(sl4, (int)pk);
    const int   idx = (int)(got & 63u);
    const float dot = __uint_as_float(got & ~63u);

    const float val = 1.f / (1.f + __expf(-fmaf(alpha, dot * inva, beta)));
    if (quad == 0) {
      svals_g[(size_t)m * 4096 + pidx + 0] = val;   // global (for gather)
      sbest_g[(size_t)m * 4096 + pidx + 0] = (unsigned char)idx;
      svalss[pl] = val;                              // LDS (for phase B)
      sidxs[pl] = (unsigned char)idx;
    }
    *(short8*)&yvs[pl][quad * 8] = avl;              // stage value half
  };

  {
    short8 a0, v0, a1, v1, a2, v2, a3, v3, a4, v4, a5, v5, a6, v6, a7, v7;
    loadpt(0, a0, v0); loadpt(1, a1, v1); loadpt(2, a2, v2); loadpt(3, a3, v3);
    loadpt(4, a4, v4); loadpt(5, a5, v5); loadpt(6, a6, v6); loadpt(7, a7, v7);
    compute_tile(0, a0, v0); compute_tile(1, a1, v1);
    compute_tile(2, a2, v2); compute_tile(3, a3, v3);
    compute_tile(4, a4, v4); compute_tile(5, a5, v5);
    compute_tile(6, a6, v6); compute_tile(7, a7, v7);
  }
  __syncthreads();

  // ---- phase B: atomic-free reduction. thread: b = t>>2, g = t&3 (8 ch)
  {
    const int b = t >> 2, g = t & 3;
    float a8[8] = {0.f, 0.f, 0.f, 0.f, 0.f, 0.f, 0.f, 0.f};
    float ac = 0.f;
#pragma unroll 4
    for (int p4 = 0; p4 < 128; p4++) {
      const uc4 i4 = *(const uc4*)&sidxs[p4 * 4];
#pragma unroll
      for (int u = 0; u < 4; u++) {
        const int idx = (u == 0) ? i4.x : (u == 1) ? i4.y : (u == 2) ? i4.z : i4.w;
        if (idx == b) {
          const int p = p4 * 4 + u;
          const float val = svalss[p];
          const us8 yv = *(const us8*)&yvs[p][g * 8];
#pragma unroll
          for (int j = 0; j < 8; j++) a8[j] = fmaf(val, bf2f(yv[j]), a8[j]);
          ac += val;
        }
      }
    }
    const size_t pb = ((size_t)(m * 8 + slice)) * 64;
    f32x4 o0, o1;
    o0.x = a8[0]; o0.y = a8[1]; o0.z = a8[2]; o0.w = a8[3];
    o1.x = a8[4]; o1.y = a8[5]; o1.z = a8[6]; o1.w = a8[7];
    *(f32x4*)&accp_v[(pb + b) * 32 + g * 8]     = o0;
    *(f32x4*)&accp_v[(pb + b) * 32 + g * 8 + 4] = o1;
    if (g == 0) accp_c[pb + b] = ac;
  }
}

// ---- D: reduce partial means + gather -> nx. grid (slice8, m256), block 256.
__global__ __launch_bounds__(256) void gather_kernel(
    const float* __restrict__ accp_v, const float* __restrict__ accp_c,
    const float* __restrict__ cval_g, const float* __restrict__ svals_g,
    const unsigned char* __restrict__ sbest_g, unsigned short* __restrict__ nx) {
  const int m = blockIdx.y, slice = blockIdx.x;
  const int n = m >> 5, f = (m >> 2) & 7, s1 = (m >> 1) & 1, s2 = m & 1;
  const int t = threadIdx.x;
  __shared__ float cm[64][34];

  const size_t nbase = ((size_t)n << 14);
  const int prow0 = s1 * 64, pcol0 = s2 * 64;

  for (int i = t; i < 2048; i += 256) {
    const int b = i >> 5, q = i & 31;
    float s = cval_g[((size_t)(m * 64 + b) << 5) + q];
    float c = 1.f;
#pragma unroll
    for (int s8 = 0; s8 < 8; s8++) {
      const size_t pb = ((size_t)(m * 8 + s8)) * 64 + b;
      s += accp_v[pb * 32 + q];
      c += accp_c[pb];
    }
    cm[b][q] = s / c;
  }
  __syncthreads();

#pragma unroll
  for (int pass = 0; pass < 2; pass++) {
    const int l = slice * 512 + pass * 256 + t;
    const int p = (prow0 + (l >> 6)) * 128 + pcol0 + (l & 63);
    const float v = svals_g[(size_t)m * 4096 + l];
    const int b = sbest_g[(size_t)m * 4096 + l];
    unsigned short* nr = nx + (nbase + p) * 256 + f * 32;
#pragma unroll
    for (int q8 = 0; q8 < 4; q8++) {
      const float2 a0 = *(const float2*)&cm[b][q8 * 8];
      const float2 a1 = *(const float2*)&cm[b][q8 * 8 + 2];
      const float2 a2 = *(const float2*)&cm[b][q8 * 8 + 4];
      const float2 a3 = *(const float2*)&cm[b][q8 * 8 + 6];
      us8 o;
      o[0] = f2bf(v * a0.x); o[1] = f2bf(v * a0.y);
      o[2] = f2bf(v * a1.x); o[3] = f2bf(v * a1.y);
      o[4] = f2bf(v * a2.x); o[5] = f2bf(v * a2.y);
      o[6] = f2bf(v * a3.x); o[7] = f2bf(v * a3.y);
      *(us8*)&nr[q8 * 8] = o;
    }
  }
}

// ---------------- GN0 per-(n,c) affine coefficients from fused sums
__global__ void gn_finalize0(const float* __restrict__ sums, const float* __restrict__ g0w,
                             const float* __restrict__ g0b, float* __restrict__ scl,
                             float* __restrict__ bia) {
  const int n = blockIdx.x, c = threadIdx.x;
  const float cntinv = 1.f / (float)(CIN * PIX);
  const float mu = sums[2 * n] * cntinv;
  const float var = sums[2 * n + 1] * cntinv - mu * mu;
  const float rs = rsqrtf(var + 1e-5f);
  const float a = rs * g0w[c];
  scl[n * 256 + c] = a;
  bia[n * 256 + c] = g0b[c] - mu * a;
}

// ---------------- fold GN0 scale into MLP0 weights (per image)
__global__ void w0_scale(const unsigned short* __restrict__ w0t,
                         const float* __restrict__ scl, unsigned short* __restrict__ w0s) {
  const int n = blockIdx.y;
  const int i = blockIdx.x * 256 + threadIdx.x;   // 0..262143
  const int k = i & 511;
  unsigned short v = w0t[i];
  if (k >= 256) v = f2bf(bf2f(v) * scl[n * 256 + k - 256]);
  w0s[(size_t)n * 262144 + i] = v;
}

// ---------------- effective MLP0 bias: b0e[n][o] = b0[o] + sum_k W0n[o][k]*bia[n][k]
__global__ void b0_eff(const unsigned short* __restrict__ w0t, const float* __restrict__ b0,
                       const float* __restrict__ bia, float* __restrict__ b0e) {
  const int n = blockIdx.y;
  const int o = blockIdx.x * 256 + threadIdx.x;   // 0..511
  float s = b0[o];
  const unsigned short* wr = w0t + (size_t)o * 512 + 256;
  const float* br = bia + n * 256;
#pragma unroll 4
  for (int k = 0; k < 256; k++) s = fmaf(bf2f(wr[k]), br[k], s);
  b0e[n * 512 + o] = s;
}

// ------------------- final: GN1 affine + layer_scale + residual, NHWC->NCHW
__global__ __launch_bounds__(256) void final_transpose(
    const unsigned short* __restrict__ u, const float* __restrict__ x,
    const float* __restrict__ sums, const float* __restrict__ g1w,
    const float* __restrict__ g1b, const float* __restrict__ lsc,
    float* __restrict__ out) {
  __shared__ float tile[64][68];
  const int t = threadIdx.x;
  const int p0 = blockIdx.x * 64, c0 = blockIdx.y * 64, n = blockIdx.z;
  {
    const int pl = t >> 2, g = t & 3;
    const unsigned short* up = u + ((((size_t)n << 14) + p0 + pl) << 8) + c0 + g * 16;
    const us8 v0 = *(const us8*)up;
    const us8 v1 = *(const us8*)(up + 8);
#pragma unroll
    for (int j = 0; j < 8; j++) {
      tile[pl][g * 16 + j] = bf2f(v0[j]);
      tile[pl][g * 16 + 8 + j] = bf2f(v1[j]);
    }
  }
  __syncthreads();
  {
    const int cl = t >> 2, g = t & 3;
    const int c = c0 + cl;
    const float cntinv = 1.f / (float)(CIN * PIX);
    const float mu = sums[2 * n] * cntinv;
    const float var = sums[2 * n + 1] * cntinv - mu * mu;
    const float rs = rsqrtf(var + 1e-5f);
    const float gw = rs * g1w[c] * lsc[c];
    const float gb = (g1b[c] - mu * rs * g1w[c]) * lsc[c];
    const size_t rowb = ((size_t)(n * 256 + c) << 14) + p0 + g * 16;
#pragma unroll
    for (int q = 0; q < 4; q++) {
      const float4 xv = *(const float4*)(x + rowb + q * 4);
      float4 o;
      o.x = fmaf(tile[g * 16 + q * 4][cl], gw, gb) + xv.x;
      o.y = fmaf(tile[g * 16 + q * 4 + 1][cl], gw, gb) + xv.y;
      o.z = fmaf(tile[g * 16 + q * 4 + 2][cl], gw, gb) + xv.z;
      o.w = fmaf(tile[g * 16 + q * 4 + 3][cl], gw, gb) + xv.w;
      *(float4*)(out + rowb + q * 4) = o;
    }
  }
}

// ---------------------------------------------------------------- launch
extern "C" void kernel_launch(void* const* d_in, const int* in_sizes, int n_in,
                              void* d_out, int out_size, void* d_ws, size_t ws_size,
                              hipStream_t stream) {
  const float* x       = (const float*)d_in[0];
  const float* proj_w  = (const float*)d_in[1];
  const float* proj_b  = (const float*)d_in[2];
  const float* merge_w = (const float*)d_in[3];
  const float* merge_b = (const float*)d_in[4];
  const float* alpha   = (const float*)d_in[5];
  const float* beta    = (const float*)d_in[6];
  const float* g0w     = (const float*)d_in[7];
  const float* g0b     = (const float*)d_in[8];
  const float* w0      = (const float*)d_in[9];
  const float* b0      = (const float*)d_in[10];
  const float* w1      = (const float*)d_in[11];
  const float* b1      = (const float*)d_in[12];
  const float* g1w     = (const float*)d_in[13];
  const float* g1b     = (const float*)d_in[14];
  const float* lsc     = (const float*)d_in[15];
  float* out = (float*)d_out;

  // workspace (ushort units), ~274 MB; newx + cluster scratch live in d_out
  unsigned short* wsu = (unsigned short*)d_ws;
  unsigned short* xT  = wsu;                      // 8*16384*256
  unsigned short* y   = xT + (size_t)33554432;    // 8*16384*512 (reused as h)
  unsigned short* nx  = y + (size_t)67108864;     // 8*16384*256 (reused as u)
  unsigned short* pw  = nx + (size_t)33554432;    // 512*256
  unsigned short* mw  = pw + 131072;              // 256*256
  unsigned short* w0t = mw + 65536;               // 512*512
  unsigned short* w1t = w0t + 262144;             // 256*512
  unsigned short* w0s = w1t + 131072;             // 8*512*512
  float* sums = (float*)(w0s + (size_t)2097152);  // 32
  float* scl0 = sums + 32;                        // 8*256
  float* bia0 = scl0 + 2048;                      // 8*256
  float* b0e  = bia0 + 2048;                      // 8*512
  unsigned short* newx = (unsigned short*)d_out;  // scratch inside out (64MB)

  // cluster scratch in the upper half of d_out (dead before final_transpose)
  float* svals_g = (float*)((char*)d_out + 67108864);       // 256*4096 f32 (4MB)
  float* cval_g  = svals_g + 1048576;                       // 256*64*32 f32 (2MB)
  float* accp_v  = cval_g + 524288;                         // 256*8*64*32 f32 (16.8MB)
  float* accp_c  = accp_v + 4194304;                        // 256*8*64 f32 (0.5MB)
  unsigned short* cpnh_g = (unsigned short*)(accp_c + 131072);  // 256*64*32 bf16 (1MB)
  unsigned char*  sbest_g = (unsigned char*)(cpnh_g + 524288);  // 256*4096 u8 (1MB)

  zero_kernel<<<1, 64, 0, stream>>>(sums, 32);
  prep_weights<<<2304, 256, 0, stream>>>(proj_w, merge_w, w0, w1, pw, mw, w0t, w1t);
  x_to_nhwc<<<dim3(256, 4, NB), 256, 0, stream>>>(x, xT);

  // proj: y[n][p][512] = pw @ xT
  mfma_gemm<false, false, false><<<dim3(128, 4, NB), 256, 0, stream>>>(
      pw, proj_b, xT, nullptr, y, 512, 256, 256, 0, 0, nullptr);

  // cluster (split)
  centers_kernel<<<dim3(4, 256), 256, 0, stream>>>(y, cpnh_g, cval_g);
  assign_kernel<<<dim3(8, 256), 256, 0, stream>>>(
      y, cpnh_g, alpha, beta, svals_g, sbest_g, accp_v, accp_c);
  gather_kernel<<<dim3(8, 256), 256, 0, stream>>>(
      accp_v, accp_c, cval_g, svals_g, sbest_g, nx);

  // merge: newx = mw @ nx, fused GN0 stats -> sums[0..15]
  mfma_gemm<false, false, true><<<dim3(128, 2, NB), 256, 0, stream>>>(
      mw, merge_b, nx, nullptr, newx, 256, 256, 256, 0, 0, sums);

  // GN0 affine coefficients, folded weights & bias
  gn_finalize0<<<NB, 256, 0, stream>>>(sums, g0w, g0b, scl0, bia0);
  w0_scale<<<dim3(1024, NB), 256, 0, stream>>>(w0t, scl0, w0s);
  b0_eff<<<dim3(2, NB), 256, 0, stream>>>(w0t, b0, bia0, b0e);

  // MLP0: h = gelu(w0s_n @ [xT ; newx] + b0e_n)   (h reuses y)
  mfma_gemm<true, true, false><<<dim3(128, 4, NB), 256, 0, stream>>>(
      w0s, b0e, xT, newx, y, 512, 512, 256, 262144, 512, nullptr);

  // MLP1: u = w1t @ h + b1, fused GN1 stats -> sums[16..31]   (u reuses nx)
  mfma_gemm<false, false, true><<<dim3(128, 2, NB), 256, 0, stream>>>(
      w1t, b1, y, nullptr, nx, 256, 512, 512, 0, 0, sums + 16);

  // final transpose/residual
  final_transpose<<<dim3(256, 4, NB), 256, 0, stream>>>(
      nx, x, sums + 16, g1w, g1b, lsc, out);
}